// Round 9
// baseline (131.728 us; speedup 1.0000x reference)
//
#include <hip/hip_runtime.h>
#include <hip/hip_bf16.h>
#include <stdint.h>

#define B_     32
#define CIN    128
#define COUT   128
#define KEXP   4
#define HW_    12544   // 112*112
#define NCHUNK 196     // HW_/64 pixel chunks
#define NPT    392     // HW_/32 pixel tiles (32-px, fragment unit)

typedef __attribute__((ext_vector_type(8))) short bf16x8;
typedef __attribute__((ext_vector_type(4))) float f32x4;
typedef __attribute__((ext_vector_type(16))) float f32x16;

// fp32 -> bf16 round-to-nearest-even (inputs finite)
static __device__ __forceinline__ ushort f2bf(float f) {
    uint32_t u = __builtin_bit_cast(uint32_t, f);
    u += 0x7FFFu + ((u >> 16) & 1u);
    return (ushort)(u >> 16);
}

// ===========================================================================
// FAST PATH (needs ~107MB workspace)
//
// xbf2 layout (B-fragment order for mfma_32x32x16, B = X):
//   [b][pt=px>>5][f=cin>>4][lane][j]  (lane = ((cin>>3)&1)*32 + (px&31), j=cin&7)
// wmix2 layout (A-fragment order, A = W):
//   [b][ct=cout>>5][f][lane][j]       (lane = ((cin>>3)&1)*32 + (cout&31))
// ===========================================================================

// ---------------------------------------------------------------------------
// prep: read x once (nontemporal; x dead afterwards), emit xbf2 (fragment-
// ordered bf16 -> L3-resident) + partial[b][chunk][cin] pooling sums.
// ---------------------------------------------------------------------------
__global__ __launch_bounds__(256) void prep_kernel(const float* __restrict__ x,
                                                   short* __restrict__ xbf2,
                                                   float* __restrict__ partial) {
    const int b  = blockIdx.y;
    const int cx = blockIdx.x;              // 0..195
    const int p0 = cx * 64;
    const int t  = threadIdx.x;
    const int pg  = t & 15;                 // pixel quad (0..15)
    const int cg8 = t >> 4;                 // cin octet (0..15)

    const float* __restrict__ xr = x + (size_t)b * CIN * HW_
                                 + (size_t)(cg8 * 8) * HW_ + p0 + pg * 4;
    f32x4 va[8];
    #pragma unroll
    for (int i = 0; i < 8; ++i)
        va[i] = __builtin_nontemporal_load((const f32x4*)(xr + (size_t)i * HW_));

    float ps[8];
    #pragma unroll
    for (int i = 0; i < 8; ++i) ps[i] = (va[i][0] + va[i][1]) + (va[i][2] + va[i][3]);
    #pragma unroll
    for (int m = 1; m < 16; m <<= 1) {
        #pragma unroll
        for (int i = 0; i < 8; ++i) ps[i] += __shfl_xor(ps[i], m, 64);
    }
    if (pg == 0) {
        float* pdst = partial + ((size_t)b * NCHUNK + cx) * CIN + cg8 * 8;
        f32x4 v0 = {ps[0], ps[1], ps[2], ps[3]};
        f32x4 v1 = {ps[4], ps[5], ps[6], ps[7]};
        *(f32x4*)pdst = v0;
        *(f32x4*)(pdst + 4) = v1;
    }

    short* __restrict__ xd = xbf2
        + ((size_t)(b * NPT + cx * 2 + (pg >> 3)) * 8 + (cg8 >> 1)) * 512
        + ((cg8 & 1) * 32 + (pg & 7) * 4) * 8;
    #pragma unroll
    for (int jj = 0; jj < 4; ++jj) {
        bf16x8 pk;
        #pragma unroll
        for (int i = 0; i < 8; ++i) pk[i] = (short)f2bf(va[i][jj]);
        *(bf16x8*)(xd + jj * 8) = pk;
    }
}

// ---------------------------------------------------------------------------
// gate2: reduce partials -> pooled -> softmax(K=4) -> wmix2 (A-frag order).
// ---------------------------------------------------------------------------
__global__ __launch_bounds__(256) void gate2_kernel(const float* __restrict__ partial,
                                                    const float* __restrict__ gate_w,
                                                    const float* __restrict__ gate_b,
                                                    const float* __restrict__ expert_w,
                                                    short* __restrict__ wmix2) {
    const int b = blockIdx.x;
    const int t = threadIdx.x;
    __shared__ float pl[CIN];
    if (t < CIN) {
        float s = 0.f;
        const float* pp = partial + (size_t)b * NCHUNK * CIN + t;
        for (int c = 0; c < NCHUNK; ++c) s += pp[(size_t)c * CIN];
        pl[t] = s * (1.0f / HW_);
    }
    __syncthreads();

    const int wid = t >> 6, lane = t & 63;
    __shared__ float logits[KEXP];
    __shared__ float gsh[KEXP];
    {
        float s = pl[lane] * gate_w[wid * CIN + lane]
                + pl[64 + lane] * gate_w[wid * CIN + 64 + lane];
        #pragma unroll
        for (int off = 32; off > 0; off >>= 1) s += __shfl_down(s, off, 64);
        if (lane == 0) logits[wid] = s + gate_b[wid];
    }
    __syncthreads();
    if (t == 0) {
        float m = fmaxf(fmaxf(logits[0], logits[1]), fmaxf(logits[2], logits[3]));
        float e0 = expf(logits[0] - m), e1 = expf(logits[1] - m);
        float e2 = expf(logits[2] - m), e3 = expf(logits[3] - m);
        float inv = 1.f / (e0 + e1 + e2 + e3);
        gsh[0] = e0 * inv; gsh[1] = e1 * inv; gsh[2] = e2 * inv; gsh[3] = e3 * inv;
    }
    __syncthreads();
    const float g0 = gsh[0], g1 = gsh[1], g2 = gsh[2], g3 = gsh[3];
    for (int idx = t; idx < COUT * CIN; idx += 256) {
        float w = g0 * expert_w[idx]
                + g1 * expert_w[COUT * CIN + idx]
                + g2 * expert_w[2 * COUT * CIN + idx]
                + g3 * expert_w[3 * COUT * CIN + idx];
        const int o = idx >> 7, c = idx & 127;   // cout, cin
        const int dst = ((b * 4 + (o >> 5)) * 8 + (c >> 4)) * 512
                      + (((c >> 3) & 1) * 32 + (o & 31)) * 8 + (c & 7);
        wmix2[dst] = (short)f2bf(w);
    }
}

// ---------------------------------------------------------------------------
// conv3 v2: out[b] = W @ X via mfma_32x32x16_bf16.  A=W from 32KB linear LDS;
// B=X 1KB-dense global loads (L3-resident xbf2).  Each wave owns TWO pt
// tiles -> two independent acc chains interleaved (hides MFMA latency);
// block = 8 pt (halved W-stage count).  Bijective XCD-chunked swizzle on
// blockIdx.x (nwg=49: q=6,r=1) for L2 read/write locality.  One barrier.
// Epilogue stores: each nt dword instr writes 2 aligned full 128B lines.
// ---------------------------------------------------------------------------
__global__ __launch_bounds__(256, 4) void conv3_kernel(const short* __restrict__ xbf2,
                                                       const short* __restrict__ wmix2,
                                                       float* __restrict__ out) {
    __shared__ short wlds[4 * 8 * 512];         // 32 KB, fragment order
    const int b = blockIdx.y;
    const int t = threadIdx.x;

    // bijective XCD swizzle: nwg=49, q=6, r=1
    const int orig = blockIdx.x;
    const int xcd = orig & 7, idx = orig >> 3;
    const int wgid = (xcd < 1 ? xcd * 7 : 7 + (xcd - 1) * 6) + idx;

    {
        const short* __restrict__ wsrc = wmix2 + (size_t)b * 16384;
        #pragma unroll
        for (int pass = 0; pass < 8; ++pass) {
            uint4 v = *(const uint4*)(wsrc + pass * 2048 + t * 8);
            *(uint4*)(wlds + pass * 2048 + t * 8) = v;
        }
    }

    const int wave = t >> 6;
    const int lane = t & 63;
    const int pt0  = wgid * 8 + wave * 2;       // this wave's 2 tiles

    // B fragments for both tiles: 16 x (64 lanes x 16B = 1KB dense)
    const short* __restrict__ xb = xbf2 + ((size_t)(b * NPT + pt0) * 8) * 512 + lane * 8;
    bf16x8 b0[8], b1[8];
    #pragma unroll
    for (int f = 0; f < 8; ++f) b0[f] = *(const bf16x8*)(xb + f * 512);
    #pragma unroll
    for (int f = 0; f < 8; ++f) b1[f] = *(const bf16x8*)(xb + (8 + f) * 512);

    __syncthreads();                            // wlds ready

    const int rowadd = 4 * (lane >> 5);
    float* __restrict__ ob0 = out + (size_t)b * COUT * HW_ + pt0 * 32 + (lane & 31);
    float* __restrict__ ob1 = ob0 + 32;

    #pragma unroll
    for (int ct = 0; ct < 4; ++ct) {
        f32x16 a0, a1;
        #pragma unroll
        for (int r = 0; r < 16; ++r) { a0[r] = 0.f; a1[r] = 0.f; }

        const short* __restrict__ wl = wlds + (ct * 8) * 512 + lane * 8;
        #pragma unroll
        for (int f = 0; f < 8; ++f) {
            bf16x8 afrag = *(const bf16x8*)(wl + f * 512);
            a0 = __builtin_amdgcn_mfma_f32_32x32x16_bf16(afrag, b0[f], a0, 0, 0, 0);
            a1 = __builtin_amdgcn_mfma_f32_32x32x16_bf16(afrag, b1[f], a1, 0, 0, 0);
        }

        #pragma unroll
        for (int r = 0; r < 16; ++r) {
            const int cout = ct * 32 + (r & 3) + 8 * (r >> 2) + rowadd;
            __builtin_nontemporal_store(a0[r], ob0 + (size_t)cout * HW_);
            __builtin_nontemporal_store(a1[r], ob1 + (size_t)cout * HW_);
        }
    }
}

// ===========================================================================
// FALLBACK PATH (round-2 structure) - used if ws too small
// ===========================================================================

__global__ __launch_bounds__(256) void pool_kernel(const float* __restrict__ x,
                                                   float* __restrict__ pooled) {
    const int row = blockIdx.x;
    const float4* __restrict__ x4 = (const float4*)(x + (size_t)row * HW_);
    const int t = threadIdx.x;
    float s = 0.f;
    for (int idx = t; idx < HW_ / 4; idx += 256) {
        float4 v = x4[idx];
        s += (v.x + v.y) + (v.z + v.w);
    }
    #pragma unroll
    for (int off = 32; off > 0; off >>= 1) s += __shfl_down(s, off, 64);
    __shared__ float wsum[4];
    if ((t & 63) == 0) wsum[t >> 6] = s;
    __syncthreads();
    if (t == 0) pooled[row] = (wsum[0] + wsum[1] + wsum[2] + wsum[3]) * (1.0f / HW_);
}

__global__ __launch_bounds__(256) void gate_kernel(const float* __restrict__ pooled,
                                                   const float* __restrict__ gate_w,
                                                   const float* __restrict__ gate_b,
                                                   const float* __restrict__ expert_w,
                                                   short* __restrict__ wmix) {
    const int b = blockIdx.x;
    const int t = threadIdx.x;
    const int wid = t >> 6, lane = t & 63;
    __shared__ float logits[KEXP];
    __shared__ float gsh[KEXP];
    {
        float p0 = pooled[b * CIN + lane];
        float p1 = pooled[b * CIN + 64 + lane];
        float s = p0 * gate_w[wid * CIN + lane] + p1 * gate_w[wid * CIN + 64 + lane];
        #pragma unroll
        for (int off = 32; off > 0; off >>= 1) s += __shfl_down(s, off, 64);
        if (lane == 0) logits[wid] = s + gate_b[wid];
    }
    __syncthreads();
    if (t == 0) {
        float m = fmaxf(fmaxf(logits[0], logits[1]), fmaxf(logits[2], logits[3]));
        float e0 = expf(logits[0] - m), e1 = expf(logits[1] - m);
        float e2 = expf(logits[2] - m), e3 = expf(logits[3] - m);
        float inv = 1.f / (e0 + e1 + e2 + e3);
        gsh[0] = e0 * inv; gsh[1] = e1 * inv; gsh[2] = e2 * inv; gsh[3] = e3 * inv;
    }
    __syncthreads();
    const float g0 = gsh[0], g1 = gsh[1], g2 = gsh[2], g3 = gsh[3];
    for (int idx = t; idx < COUT * CIN; idx += 256) {
        float w = g0 * expert_w[idx]
                + g1 * expert_w[COUT * CIN + idx]
                + g2 * expert_w[2 * COUT * CIN + idx]
                + g3 * expert_w[3 * COUT * CIN + idx];
        wmix[b * COUT * CIN + idx] = (short)f2bf(w);
    }
}

__global__ __launch_bounds__(256, 4) void conv_fb_kernel(const float* __restrict__ x,
                                                         const short* __restrict__ wmix,
                                                         float* __restrict__ out) {
    __shared__ char wlds[COUT * 256];
    __shared__ char xlds[64 * 256];
    const int b  = blockIdx.y;
    const int p0 = blockIdx.x * 64;
    const int t  = threadIdx.x;

    {
        const uint4* __restrict__ wsrc = (const uint4*)(wmix + (size_t)b * COUT * CIN);
        #pragma unroll
        for (int pass = 0; pass < 8; ++pass) {
            int o  = (t >> 4) + pass * 16;
            int i4 = t & 15;
            uint4 v = wsrc[o * 16 + i4];
            *(uint4*)(wlds + o * 256 + ((i4 ^ (o & 15)) << 4)) = v;
        }
    }
    {
        const int pg = t & 15;
        const int cg = t >> 4;
        #pragma unroll
        for (int p = 0; p < 2; ++p) {
            const int cin0 = p * 64 + cg * 4;
            const float* xrow = x + (size_t)b * CIN * HW_ + (size_t)cin0 * HW_ + p0 + pg * 4;
            float va[4][4];
            #pragma unroll
            for (int i = 0; i < 4; ++i) {
                float4 v = *(const float4*)(xrow + (size_t)i * HW_);
                va[i][0] = v.x; va[i][1] = v.y; va[i][2] = v.z; va[i][3] = v.w;
            }
            #pragma unroll
            for (int j = 0; j < 4; ++j) {
                const int pix = pg * 4 + j;
                uint32_t lo = (uint32_t)f2bf(va[0][j]) | ((uint32_t)f2bf(va[1][j]) << 16);
                uint32_t hi = (uint32_t)f2bf(va[2][j]) | ((uint32_t)f2bf(va[3][j]) << 16);
                int byte = (pix * 256 + cin0 * 2) ^ ((pix & 7) << 4);
                uint2 w2; w2.x = lo; w2.y = hi;
                *(uint2*)(xlds + byte) = w2;
            }
        }
    }

    const int wave = t >> 6;
    const int lane = t & 63;
    const int n = lane & 15;
    const int h = lane >> 4;

    __syncthreads();

    bf16x8 xfrag[4];
    {
        const int pixl = wave * 16 + n;
        #pragma unroll
        for (int kk = 0; kk < 4; ++kk) {
            int byte = (pixl * 256 + kk * 64 + h * 16) ^ ((pixl & 7) << 4);
            xfrag[kk] = *(const bf16x8*)(xlds + byte);
        }
    }

    f32x4 acc[8];
    #pragma unroll
    for (int ot = 0; ot < 8; ++ot) acc[ot] = (f32x4){0.f, 0.f, 0.f, 0.f};

    #pragma unroll
    for (int ot = 0; ot < 8; ++ot) {
        const int o = ot * 16 + n;
        #pragma unroll
        for (int kk = 0; kk < 4; ++kk) {
            bf16x8 wfrag = *(const bf16x8*)(wlds + o * 256 + (((kk * 4 + h) ^ n) << 4));
            acc[ot] = __builtin_amdgcn_mfma_f32_16x16x32_bf16(xfrag[kk], wfrag, acc[ot], 0, 0, 0);
        }
    }

    float* __restrict__ ob = out + (size_t)b * COUT * HW_ + p0 + wave * 16 + h * 4;
    #pragma unroll
    for (int ot = 0; ot < 8; ++ot)
        __builtin_nontemporal_store(acc[ot], (f32x4*)(ob + (size_t)(ot * 16 + n) * HW_));
}

// ---------------------------------------------------------------------------
extern "C" void kernel_launch(void* const* d_in, const int* in_sizes, int n_in,
                              void* d_out, int out_size, void* d_ws, size_t ws_size,
                              hipStream_t stream) {
    const float* x        = (const float*)d_in[0];
    const float* expert_w = (const float*)d_in[1];
    const float* gate_w   = (const float*)d_in[2];
    const float* gate_b   = (const float*)d_in[3];
    float* out = (float*)d_out;

    const size_t PARTIAL_B = (size_t)B_ * NCHUNK * CIN * 4;     // 3,211,264
    const size_t WMIX_B    = (size_t)B_ * COUT * CIN * 2;       // 1,048,576
    const size_t XBF_B     = (size_t)B_ * HW_ * CIN * 2;        // 102,760,448
    const size_t NEED      = PARTIAL_B + WMIX_B + XBF_B;

    if (ws_size >= NEED) {
        float* partial = (float*)d_ws;
        short* wmix2   = (short*)((char*)d_ws + PARTIAL_B);
        short* xbf2    = (short*)((char*)d_ws + PARTIAL_B + WMIX_B);

        prep_kernel<<<dim3(NCHUNK, B_), 256, 0, stream>>>(x, xbf2, partial);
        gate2_kernel<<<dim3(B_), 256, 0, stream>>>(partial, gate_w, gate_b, expert_w, wmix2);
        conv3_kernel<<<dim3(NPT / 8, B_), 256, 0, stream>>>(xbf2, wmix2, out);
    } else {
        float* pooled = (float*)d_ws;                           // 16 KB
        short* wmix   = (short*)((char*)d_ws + 16384);          // 1 MB
        pool_kernel<<<dim3(B_ * CIN), 256, 0, stream>>>(x, pooled);
        gate_kernel<<<dim3(B_), 256, 0, stream>>>(pooled, gate_w, gate_b, expert_w, wmix);
        conv_fb_kernel<<<dim3(HW_ / 64, B_), 256, 0, stream>>>(x, wmix, out);
    }
}

// Round 10
// 130.861 us; speedup vs baseline: 1.0066x; 1.0066x over previous
//
#include <hip/hip_runtime.h>
#include <hip/hip_bf16.h>
#include <stdint.h>

#define B_     32
#define CIN    128
#define COUT   128
#define KEXP   4
#define HW_    12544   // 112*112
#define NCHUNK 196     // HW_/64 pixel chunks
#define NPT    392     // HW_/32 pixel tiles (32-px, fragment unit)

typedef __attribute__((ext_vector_type(8))) short bf16x8;
typedef __attribute__((ext_vector_type(4))) float f32x4;
typedef __attribute__((ext_vector_type(16))) float f32x16;

// fp32 -> bf16 RNE via native conversion (compiler emits v_cvt / packs pairs)
static __device__ __forceinline__ short f2bf(float f) {
    __hip_bfloat16 h = __float2bfloat16(f);
    return __builtin_bit_cast(short, h);
}

// ===========================================================================
// FAST PATH (needs ~107MB workspace)
//
// xbf2 layout (B-fragment order for mfma_32x32x16, B = X):
//   [b][pt=px>>5][f=cin>>4][lane][j]  (lane = ((cin>>3)&1)*32 + (px&31), j=cin&7)
// wmix2 layout (A-fragment order, A = W):
//   [b][ct=cout>>5][f][lane][j]       (lane = ((cin>>3)&1)*32 + (cout&31))
// ===========================================================================

// ---------------------------------------------------------------------------
// prep: read x once (normal caching loads), emit xbf2 (fragment-ordered
// bf16) + partial[b][chunk][cin] pooling sums.
// ---------------------------------------------------------------------------
__global__ __launch_bounds__(256) void prep_kernel(const float* __restrict__ x,
                                                   short* __restrict__ xbf2,
                                                   float* __restrict__ partial) {
    const int b  = blockIdx.y;
    const int cx = blockIdx.x;              // 0..195
    const int p0 = cx * 64;
    const int t  = threadIdx.x;
    const int pg  = t & 15;                 // pixel quad (0..15)
    const int cg8 = t >> 4;                 // cin octet (0..15)

    const float* __restrict__ xr = x + (size_t)b * CIN * HW_
                                 + (size_t)(cg8 * 8) * HW_ + p0 + pg * 4;
    f32x4 va[8];
    #pragma unroll
    for (int i = 0; i < 8; ++i)
        va[i] = *(const f32x4*)(xr + (size_t)i * HW_);

    float ps[8];
    #pragma unroll
    for (int i = 0; i < 8; ++i) ps[i] = (va[i][0] + va[i][1]) + (va[i][2] + va[i][3]);
    #pragma unroll
    for (int m = 1; m < 16; m <<= 1) {
        #pragma unroll
        for (int i = 0; i < 8; ++i) ps[i] += __shfl_xor(ps[i], m, 64);
    }
    if (pg == 0) {
        float* pdst = partial + ((size_t)b * NCHUNK + cx) * CIN + cg8 * 8;
        f32x4 v0 = {ps[0], ps[1], ps[2], ps[3]};
        f32x4 v1 = {ps[4], ps[5], ps[6], ps[7]};
        *(f32x4*)pdst = v0;
        *(f32x4*)(pdst + 4) = v1;
    }

    short* __restrict__ xd = xbf2
        + ((size_t)(b * NPT + cx * 2 + (pg >> 3)) * 8 + (cg8 >> 1)) * 512
        + ((cg8 & 1) * 32 + (pg & 7) * 4) * 8;
    #pragma unroll
    for (int jj = 0; jj < 4; ++jj) {
        bf16x8 pk;
        #pragma unroll
        for (int i = 0; i < 8; ++i) pk[i] = f2bf(va[i][jj]);
        *(bf16x8*)(xd + jj * 8) = pk;
    }
}

// ---------------------------------------------------------------------------
// gate2: reduce partials -> pooled -> softmax(K=4) -> wmix2 (A-frag order).
// ---------------------------------------------------------------------------
__global__ __launch_bounds__(256) void gate2_kernel(const float* __restrict__ partial,
                                                    const float* __restrict__ gate_w,
                                                    const float* __restrict__ gate_b,
                                                    const float* __restrict__ expert_w,
                                                    short* __restrict__ wmix2) {
    const int b = blockIdx.x;
    const int t = threadIdx.x;
    __shared__ float pl[CIN];
    if (t < CIN) {
        float s = 0.f;
        const float* pp = partial + (size_t)b * NCHUNK * CIN + t;
        for (int c = 0; c < NCHUNK; ++c) s += pp[(size_t)c * CIN];
        pl[t] = s * (1.0f / HW_);
    }
    __syncthreads();

    const int wid = t >> 6, lane = t & 63;
    __shared__ float logits[KEXP];
    __shared__ float gsh[KEXP];
    {
        float s = pl[lane] * gate_w[wid * CIN + lane]
                + pl[64 + lane] * gate_w[wid * CIN + 64 + lane];
        #pragma unroll
        for (int off = 32; off > 0; off >>= 1) s += __shfl_down(s, off, 64);
        if (lane == 0) logits[wid] = s + gate_b[wid];
    }
    __syncthreads();
    if (t == 0) {
        float m = fmaxf(fmaxf(logits[0], logits[1]), fmaxf(logits[2], logits[3]));
        float e0 = expf(logits[0] - m), e1 = expf(logits[1] - m);
        float e2 = expf(logits[2] - m), e3 = expf(logits[3] - m);
        float inv = 1.f / (e0 + e1 + e2 + e3);
        gsh[0] = e0 * inv; gsh[1] = e1 * inv; gsh[2] = e2 * inv; gsh[3] = e3 * inv;
    }
    __syncthreads();
    const float g0 = gsh[0], g1 = gsh[1], g2 = gsh[2], g3 = gsh[3];
    for (int idx = t; idx < COUT * CIN; idx += 256) {
        float w = g0 * expert_w[idx]
                + g1 * expert_w[COUT * CIN + idx]
                + g2 * expert_w[2 * COUT * CIN + idx]
                + g3 * expert_w[3 * COUT * CIN + idx];
        const int o = idx >> 7, c = idx & 127;   // cout, cin
        const int dst = ((b * 4 + (o >> 5)) * 8 + (c >> 4)) * 512
                      + (((c >> 3) & 1) * 32 + (o & 31)) * 8 + (c & 7);
        wmix2[dst] = f2bf(w);
    }
}

// ---------------------------------------------------------------------------
// conv3: out[b] = W @ X via mfma_32x32x16_bf16.  A=W from 32KB linear LDS;
// B=X 1KB-dense global loads.  Wave owns 2 pt tiles (independent acc
// chains); block = 8 pt.  Bijective XCD swizzle (nwg=49: q=6,r=1).
// Epilogue: each nt dword store instr writes 2 aligned full 128B lines.
// ---------------------------------------------------------------------------
__global__ __launch_bounds__(256, 4) void conv3_kernel(const short* __restrict__ xbf2,
                                                       const short* __restrict__ wmix2,
                                                       float* __restrict__ out) {
    __shared__ short wlds[4 * 8 * 512];         // 32 KB, fragment order
    const int b = blockIdx.y;
    const int t = threadIdx.x;

    // bijective XCD swizzle: nwg=49, q=6, r=1
    const int orig = blockIdx.x;
    const int xcd = orig & 7, idx = orig >> 3;
    const int wgid = (xcd < 1 ? xcd * 7 : 7 + (xcd - 1) * 6) + idx;

    {
        const short* __restrict__ wsrc = wmix2 + (size_t)b * 16384;
        #pragma unroll
        for (int pass = 0; pass < 8; ++pass) {
            uint4 v = *(const uint4*)(wsrc + pass * 2048 + t * 8);
            *(uint4*)(wlds + pass * 2048 + t * 8) = v;
        }
    }

    const int wave = t >> 6;
    const int lane = t & 63;
    const int pt0  = wgid * 8 + wave * 2;       // this wave's 2 tiles

    const short* __restrict__ xb = xbf2 + ((size_t)(b * NPT + pt0) * 8) * 512 + lane * 8;
    bf16x8 b0[8], b1[8];
    #pragma unroll
    for (int f = 0; f < 8; ++f) b0[f] = *(const bf16x8*)(xb + f * 512);
    #pragma unroll
    for (int f = 0; f < 8; ++f) b1[f] = *(const bf16x8*)(xb + (8 + f) * 512);

    __syncthreads();                            // wlds ready

    const int rowadd = 4 * (lane >> 5);
    float* __restrict__ ob0 = out + (size_t)b * COUT * HW_ + pt0 * 32 + (lane & 31);
    float* __restrict__ ob1 = ob0 + 32;

    #pragma unroll
    for (int ct = 0; ct < 4; ++ct) {
        f32x16 a0, a1;
        #pragma unroll
        for (int r = 0; r < 16; ++r) { a0[r] = 0.f; a1[r] = 0.f; }

        const short* __restrict__ wl = wlds + (ct * 8) * 512 + lane * 8;
        #pragma unroll
        for (int f = 0; f < 8; ++f) {
            bf16x8 afrag = *(const bf16x8*)(wl + f * 512);
            a0 = __builtin_amdgcn_mfma_f32_32x32x16_bf16(afrag, b0[f], a0, 0, 0, 0);
            a1 = __builtin_amdgcn_mfma_f32_32x32x16_bf16(afrag, b1[f], a1, 0, 0, 0);
        }

        #pragma unroll
        for (int r = 0; r < 16; ++r) {
            const int cout = ct * 32 + (r & 3) + 8 * (r >> 2) + rowadd;
            __builtin_nontemporal_store(a0[r], ob0 + (size_t)cout * HW_);
            __builtin_nontemporal_store(a1[r], ob1 + (size_t)cout * HW_);
        }
    }
}

// ===========================================================================
// FALLBACK PATH (round-2 structure) - used if ws too small
// ===========================================================================

__global__ __launch_bounds__(256) void pool_kernel(const float* __restrict__ x,
                                                   float* __restrict__ pooled) {
    const int row = blockIdx.x;
    const float4* __restrict__ x4 = (const float4*)(x + (size_t)row * HW_);
    const int t = threadIdx.x;
    float s = 0.f;
    for (int idx = t; idx < HW_ / 4; idx += 256) {
        float4 v = x4[idx];
        s += (v.x + v.y) + (v.z + v.w);
    }
    #pragma unroll
    for (int off = 32; off > 0; off >>= 1) s += __shfl_down(s, off, 64);
    __shared__ float wsum[4];
    if ((t & 63) == 0) wsum[t >> 6] = s;
    __syncthreads();
    if (t == 0) pooled[row] = (wsum[0] + wsum[1] + wsum[2] + wsum[3]) * (1.0f / HW_);
}

__global__ __launch_bounds__(256) void gate_kernel(const float* __restrict__ pooled,
                                                   const float* __restrict__ gate_w,
                                                   const float* __restrict__ gate_b,
                                                   const float* __restrict__ expert_w,
                                                   short* __restrict__ wmix) {
    const int b = blockIdx.x;
    const int t = threadIdx.x;
    const int wid = t >> 6, lane = t & 63;
    __shared__ float logits[KEXP];
    __shared__ float gsh[KEXP];
    {
        float p0 = pooled[b * CIN + lane];
        float p1 = pooled[b * CIN + 64 + lane];
        float s = p0 * gate_w[wid * CIN + lane] + p1 * gate_w[wid * CIN + 64 + lane];
        #pragma unroll
        for (int off = 32; off > 0; off >>= 1) s += __shfl_down(s, off, 64);
        if (lane == 0) logits[wid] = s + gate_b[wid];
    }
    __syncthreads();
    if (t == 0) {
        float m = fmaxf(fmaxf(logits[0], logits[1]), fmaxf(logits[2], logits[3]));
        float e0 = expf(logits[0] - m), e1 = expf(logits[1] - m);
        float e2 = expf(logits[2] - m), e3 = expf(logits[3] - m);
        float inv = 1.f / (e0 + e1 + e2 + e3);
        gsh[0] = e0 * inv; gsh[1] = e1 * inv; gsh[2] = e2 * inv; gsh[3] = e3 * inv;
    }
    __syncthreads();
    const float g0 = gsh[0], g1 = gsh[1], g2 = gsh[2], g3 = gsh[3];
    for (int idx = t; idx < COUT * CIN; idx += 256) {
        float w = g0 * expert_w[idx]
                + g1 * expert_w[COUT * CIN + idx]
                + g2 * expert_w[2 * COUT * CIN + idx]
                + g3 * expert_w[3 * COUT * CIN + idx];
        wmix[b * COUT * CIN + idx] = f2bf(w);
    }
}

__global__ __launch_bounds__(256, 4) void conv_fb_kernel(const float* __restrict__ x,
                                                         const short* __restrict__ wmix,
                                                         float* __restrict__ out) {
    __shared__ char wlds[COUT * 256];
    __shared__ char xlds[64 * 256];
    const int b  = blockIdx.y;
    const int p0 = blockIdx.x * 64;
    const int t  = threadIdx.x;

    {
        const uint4* __restrict__ wsrc = (const uint4*)(wmix + (size_t)b * COUT * CIN);
        #pragma unroll
        for (int pass = 0; pass < 8; ++pass) {
            int o  = (t >> 4) + pass * 16;
            int i4 = t & 15;
            uint4 v = wsrc[o * 16 + i4];
            *(uint4*)(wlds + o * 256 + ((i4 ^ (o & 15)) << 4)) = v;
        }
    }
    {
        const int pg = t & 15;
        const int cg = t >> 4;
        #pragma unroll
        for (int p = 0; p < 2; ++p) {
            const int cin0 = p * 64 + cg * 4;
            const float* xrow = x + (size_t)b * CIN * HW_ + (size_t)cin0 * HW_ + p0 + pg * 4;
            float va[4][4];
            #pragma unroll
            for (int i = 0; i < 4; ++i) {
                float4 v = *(const float4*)(xrow + (size_t)i * HW_);
                va[i][0] = v.x; va[i][1] = v.y; va[i][2] = v.z; va[i][3] = v.w;
            }
            #pragma unroll
            for (int j = 0; j < 4; ++j) {
                const int pix = pg * 4 + j;
                uint32_t lo = (uint32_t)(ushort)f2bf(va[0][j]) | ((uint32_t)(ushort)f2bf(va[1][j]) << 16);
                uint32_t hi = (uint32_t)(ushort)f2bf(va[2][j]) | ((uint32_t)(ushort)f2bf(va[3][j]) << 16);
                int byte = (pix * 256 + cin0 * 2) ^ ((pix & 7) << 4);
                uint2 w2; w2.x = lo; w2.y = hi;
                *(uint2*)(xlds + byte) = w2;
            }
        }
    }

    const int wave = t >> 6;
    const int lane = t & 63;
    const int n = lane & 15;
    const int h = lane >> 4;

    __syncthreads();

    bf16x8 xfrag[4];
    {
        const int pixl = wave * 16 + n;
        #pragma unroll
        for (int kk = 0; kk < 4; ++kk) {
            int byte = (pixl * 256 + kk * 64 + h * 16) ^ ((pixl & 7) << 4);
            xfrag[kk] = *(const bf16x8*)(xlds + byte);
        }
    }

    f32x4 acc[8];
    #pragma unroll
    for (int ot = 0; ot < 8; ++ot) acc[ot] = (f32x4){0.f, 0.f, 0.f, 0.f};

    #pragma unroll
    for (int ot = 0; ot < 8; ++ot) {
        const int o = ot * 16 + n;
        #pragma unroll
        for (int kk = 0; kk < 4; ++kk) {
            bf16x8 wfrag = *(const bf16x8*)(wlds + o * 256 + (((kk * 4 + h) ^ n) << 4));
            acc[ot] = __builtin_amdgcn_mfma_f32_16x16x32_bf16(xfrag[kk], wfrag, acc[ot], 0, 0, 0);
        }
    }

    float* __restrict__ ob = out + (size_t)b * COUT * HW_ + p0 + wave * 16 + h * 4;
    #pragma unroll
    for (int ot = 0; ot < 8; ++ot)
        __builtin_nontemporal_store(acc[ot], (f32x4*)(ob + (size_t)(ot * 16 + n) * HW_));
}

// ---------------------------------------------------------------------------
extern "C" void kernel_launch(void* const* d_in, const int* in_sizes, int n_in,
                              void* d_out, int out_size, void* d_ws, size_t ws_size,
                              hipStream_t stream) {
    const float* x        = (const float*)d_in[0];
    const float* expert_w = (const float*)d_in[1];
    const float* gate_w   = (const float*)d_in[2];
    const float* gate_b   = (const float*)d_in[3];
    float* out = (float*)d_out;

    const size_t PARTIAL_B = (size_t)B_ * NCHUNK * CIN * 4;     // 3,211,264
    const size_t WMIX_B    = (size_t)B_ * COUT * CIN * 2;       // 1,048,576
    const size_t XBF_B     = (size_t)B_ * HW_ * CIN * 2;        // 102,760,448
    const size_t NEED      = PARTIAL_B + WMIX_B + XBF_B;

    if (ws_size >= NEED) {
        float* partial = (float*)d_ws;
        short* wmix2   = (short*)((char*)d_ws + PARTIAL_B);
        short* xbf2    = (short*)((char*)d_ws + PARTIAL_B + WMIX_B);

        prep_kernel<<<dim3(NCHUNK, B_), 256, 0, stream>>>(x, xbf2, partial);
        gate2_kernel<<<dim3(B_), 256, 0, stream>>>(partial, gate_w, gate_b, expert_w, wmix2);
        conv3_kernel<<<dim3(NPT / 8, B_), 256, 0, stream>>>(xbf2, wmix2, out);
    } else {
        float* pooled = (float*)d_ws;                           // 16 KB
        short* wmix   = (short*)((char*)d_ws + 16384);          // 1 MB
        pool_kernel<<<dim3(B_ * CIN), 256, 0, stream>>>(x, pooled);
        gate_kernel<<<dim3(B_), 256, 0, stream>>>(pooled, gate_w, gate_b, expert_w, wmix);
        conv_fb_kernel<<<dim3(HW_ / 64, B_), 256, 0, stream>>>(x, wmix, out);
    }
}

// Round 12
// 129.681 us; speedup vs baseline: 1.0158x; 1.0091x over previous
//
#include <hip/hip_runtime.h>
#include <hip/hip_bf16.h>
#include <stdint.h>

#define B_     32
#define CIN    128
#define COUT   128
#define KEXP   4
#define HW_    12544   // 112*112
#define NCHUNK 196     // 64-px chunks per b
#define NPT    392     // 32-px tiles per b

typedef __attribute__((ext_vector_type(8))) short bf16x8;
typedef __attribute__((ext_vector_type(4))) float f32x4;
typedef __attribute__((ext_vector_type(16))) float f32x16;

// fp32 -> bf16 RNE via native conversion
static __device__ __forceinline__ short f2bf(float f) {
    __hip_bfloat16 h = __float2bfloat16(f);
    return __builtin_bit_cast(short, h);
}

// ===========================================================================
// FAST PATH (needs ~107MB workspace)
//
// xbf2 layout (B-fragment order for mfma_32x32x16, B = X):
//   [b][pt=px>>5][f=cin>>4][lane][j]  (lane = ((cin>>3)&1)*32 + (px&31), j=cin&7)
// wmix2 layout (A-fragment order, A = W):
//   [b][ct=cout>>5][f][lane][j]       (lane = ((cin>>3)&1)*32 + (cout&31))
// ===========================================================================

// ---------------------------------------------------------------------------
// prep: read x once, emit xbf2 (fragment-ordered bf16) + partial pooling sums.
// Dispatch order: (cx asc, b asc) -> xbf2 written b-ascending; conv3 consumes
// in exact REVERSE (LIFO) for maximal L3 residency hits.
// ---------------------------------------------------------------------------
__global__ __launch_bounds__(256) void prep_kernel(const float* __restrict__ x,
                                                   short* __restrict__ xbf2,
                                                   float* __restrict__ partial) {
    const int b  = blockIdx.y;
    const int cx = blockIdx.x;              // 0..195
    const int p0 = cx * 64;
    const int t  = threadIdx.x;
    const int pg  = t & 15;                 // pixel quad (0..15)
    const int cg8 = t >> 4;                 // cin octet (0..15)

    const float* __restrict__ xr = x + (size_t)b * CIN * HW_
                                 + (size_t)(cg8 * 8) * HW_ + p0 + pg * 4;
    f32x4 va[8];
    #pragma unroll
    for (int i = 0; i < 8; ++i)
        va[i] = *(const f32x4*)(xr + (size_t)i * HW_);

    float ps[8];
    #pragma unroll
    for (int i = 0; i < 8; ++i) ps[i] = (va[i][0] + va[i][1]) + (va[i][2] + va[i][3]);
    #pragma unroll
    for (int m = 1; m < 16; m <<= 1) {
        #pragma unroll
        for (int i = 0; i < 8; ++i) ps[i] += __shfl_xor(ps[i], m, 64);
    }
    if (pg == 0) {
        float* pdst = partial + ((size_t)b * NCHUNK + cx) * CIN + cg8 * 8;
        f32x4 v0 = {ps[0], ps[1], ps[2], ps[3]};
        f32x4 v1 = {ps[4], ps[5], ps[6], ps[7]};
        *(f32x4*)pdst = v0;
        *(f32x4*)(pdst + 4) = v1;
    }

    short* __restrict__ xd = xbf2
        + ((size_t)(b * NPT + cx * 2 + (pg >> 3)) * 8 + (cg8 >> 1)) * 512
        + ((cg8 & 1) * 32 + (pg & 7) * 4) * 8;
    #pragma unroll
    for (int jj = 0; jj < 4; ++jj) {
        bf16x8 pk;
        #pragma unroll
        for (int i = 0; i < 8; ++i) pk[i] = f2bf(va[i][jj]);
        *(bf16x8*)(xd + jj * 8) = pk;
    }
}

// ---------------------------------------------------------------------------
// gate2: PARALLEL partial reduction (all 256 threads: 128 cin x 2 chunk-
// halves) -> pooled -> softmax(K=4) -> wmix2 (A-frag order). Block per b.
// ---------------------------------------------------------------------------
__global__ __launch_bounds__(256) void gate2_kernel(const float* __restrict__ partial,
                                                    const float* __restrict__ gate_w,
                                                    const float* __restrict__ gate_b,
                                                    const float* __restrict__ expert_w,
                                                    short* __restrict__ wmix2) {
    const int b = blockIdx.x;
    const int t = threadIdx.x;
    __shared__ float psum[2][CIN];
    __shared__ float pl[CIN];
    {
        const int cin  = t & 127;
        const int half = t >> 7;            // 0/1
        float s = 0.f;
        const float* pp = partial + (size_t)b * NCHUNK * CIN + (size_t)(half * 98) * CIN + cin;
        #pragma unroll 7
        for (int c = 0; c < 98; ++c) s += pp[(size_t)c * CIN];
        psum[half][cin] = s;
    }
    __syncthreads();
    if (t < CIN) pl[t] = (psum[0][t] + psum[1][t]) * (1.0f / HW_);
    __syncthreads();

    const int wid = t >> 6, lane = t & 63;
    __shared__ float logits[KEXP];
    __shared__ float gsh[KEXP];
    {
        float s = pl[lane] * gate_w[wid * CIN + lane]
                + pl[64 + lane] * gate_w[wid * CIN + 64 + lane];
        #pragma unroll
        for (int off = 32; off > 0; off >>= 1) s += __shfl_down(s, off, 64);
        if (lane == 0) logits[wid] = s + gate_b[wid];
    }
    __syncthreads();
    if (t == 0) {
        float m = fmaxf(fmaxf(logits[0], logits[1]), fmaxf(logits[2], logits[3]));
        float e0 = expf(logits[0] - m), e1 = expf(logits[1] - m);
        float e2 = expf(logits[2] - m), e3 = expf(logits[3] - m);
        float inv = 1.f / (e0 + e1 + e2 + e3);
        gsh[0] = e0 * inv; gsh[1] = e1 * inv; gsh[2] = e2 * inv; gsh[3] = e3 * inv;
    }
    __syncthreads();
    const float g0 = gsh[0], g1 = gsh[1], g2 = gsh[2], g3 = gsh[3];
    for (int idx = t; idx < COUT * CIN; idx += 256) {
        float w = g0 * expert_w[idx]
                + g1 * expert_w[COUT * CIN + idx]
                + g2 * expert_w[2 * COUT * CIN + idx]
                + g3 * expert_w[3 * COUT * CIN + idx];
        const int o = idx >> 7, c = idx & 127;   // cout, cin
        const int dst = ((b * 4 + (o >> 5)) * 8 + (c >> 4)) * 512
                      + (((c >> 3) & 1) * 32 + (o & 31)) * 8 + (c & 7);
        wmix2[dst] = f2bf(w);
    }
}

// ---------------------------------------------------------------------------
// conv3: out[b] = W @ X via mfma_32x32x16_bf16.  A=W from 32KB linear LDS;
// B=X 1KB-dense global loads.  CONSUMES xbf2 IN REVERSE of prep's write
// order (b desc, ug desc) -> LIFO L3 hits.  Wave owns 2 pt tiles
// (independent acc chains); XCD-bijective swizzle on top.  One barrier.
// Epilogue: each nt dword store writes 2 aligned full 128B lines.
// ---------------------------------------------------------------------------
__global__ __launch_bounds__(256, 4) void conv3_kernel(const short* __restrict__ xbf2,
                                                       const short* __restrict__ wmix2,
                                                       float* __restrict__ out) {
    __shared__ short wlds[4 * 8 * 512];         // 32 KB, fragment order
    const int t = threadIdx.x;

    // reverse-b: earliest-dispatched blocks eat the freshest xbf2
    const int b = (B_ - 1) - blockIdx.y;

    // bijective XCD swizzle (nwg=49, q=6, r=1), then reverse ug
    const int orig = blockIdx.x;
    const int xcd = orig & 7, idx = orig >> 3;
    const int wgid = (xcd < 1 ? xcd * 7 : 7 + (xcd - 1) * 6) + idx;
    const int ug = 48 - wgid;

    {
        const short* __restrict__ wsrc = wmix2 + (size_t)b * 16384;
        #pragma unroll
        for (int pass = 0; pass < 8; ++pass) {
            uint4 v = *(const uint4*)(wsrc + pass * 2048 + t * 8);
            *(uint4*)(wlds + pass * 2048 + t * 8) = v;
        }
    }

    const int wave = t >> 6;
    const int lane = t & 63;
    const int pt0  = ug * 8 + wave * 2;         // this wave's 2 tiles

    const short* __restrict__ xb = xbf2 + ((size_t)(b * NPT + pt0) * 8) * 512 + lane * 8;
    bf16x8 b0[8], b1[8];
    #pragma unroll
    for (int f = 0; f < 8; ++f) b0[f] = *(const bf16x8*)(xb + f * 512);
    #pragma unroll
    for (int f = 0; f < 8; ++f) b1[f] = *(const bf16x8*)(xb + (8 + f) * 512);

    __syncthreads();                            // wlds ready

    const int rowadd = 4 * (lane >> 5);
    float* __restrict__ ob0 = out + (size_t)b * COUT * HW_ + pt0 * 32 + (lane & 31);
    float* __restrict__ ob1 = ob0 + 32;

    #pragma unroll
    for (int ct = 0; ct < 4; ++ct) {
        f32x16 a0, a1;
        #pragma unroll
        for (int r = 0; r < 16; ++r) { a0[r] = 0.f; a1[r] = 0.f; }

        const short* __restrict__ wl = wlds + (ct * 8) * 512 + lane * 8;
        #pragma unroll
        for (int f = 0; f < 8; ++f) {
            bf16x8 afrag = *(const bf16x8*)(wl + f * 512);
            a0 = __builtin_amdgcn_mfma_f32_32x32x16_bf16(afrag, b0[f], a0, 0, 0, 0);
            a1 = __builtin_amdgcn_mfma_f32_32x32x16_bf16(afrag, b1[f], a1, 0, 0, 0);
        }

        #pragma unroll
        for (int r = 0; r < 16; ++r) {
            const int cout = ct * 32 + (r & 3) + 8 * (r >> 2) + rowadd;
            __builtin_nontemporal_store(a0[r], ob0 + (size_t)cout * HW_);
            __builtin_nontemporal_store(a1[r], ob1 + (size_t)cout * HW_);
        }
    }
}

// ===========================================================================
// FALLBACK PATH (round-2 structure) - used if ws too small
// ===========================================================================

__global__ __launch_bounds__(256) void pool_kernel(const float* __restrict__ x,
                                                   float* __restrict__ pooled) {
    const int row = blockIdx.x;
    const float4* __restrict__ x4 = (const float4*)(x + (size_t)row * HW_);
    const int t = threadIdx.x;
    float s = 0.f;
    for (int idx = t; idx < HW_ / 4; idx += 256) {
        float4 v = x4[idx];
        s += (v.x + v.y) + (v.z + v.w);
    }
    #pragma unroll
    for (int off = 32; off > 0; off >>= 1) s += __shfl_down(s, off, 64);
    __shared__ float wsum[4];
    if ((t & 63) == 0) wsum[t >> 6] = s;
    __syncthreads();
    if (t == 0) pooled[row] = (wsum[0] + wsum[1] + wsum[2] + wsum[3]) * (1.0f / HW_);
}

__global__ __launch_bounds__(256) void gate_kernel(const float* __restrict__ pooled,
                                                   const float* __restrict__ gate_w,
                                                   const float* __restrict__ gate_b,
                                                   const float* __restrict__ expert_w,
                                                   short* __restrict__ wmix) {
    const int b = blockIdx.x;
    const int t = threadIdx.x;
    const int wid = t >> 6, lane = t & 63;
    __shared__ float logits[KEXP];
    __shared__ float gsh[KEXP];
    {
        float p0 = pooled[b * CIN + lane];
        float p1 = pooled[b * CIN + 64 + lane];
        float s = p0 * gate_w[wid * CIN + lane] + p1 * gate_w[wid * CIN + 64 + lane];
        #pragma unroll
        for (int off = 32; off > 0; off >>= 1) s += __shfl_down(s, off, 64);
        if (lane == 0) logits[wid] = s + gate_b[wid];
    }
    __syncthreads();
    if (t == 0) {
        float m = fmaxf(fmaxf(logits[0], logits[1]), fmaxf(logits[2], logits[3]));
        float e0 = expf(logits[0] - m), e1 = expf(logits[1] - m);
        float e2 = expf(logits[2] - m), e3 = expf(logits[3] - m);
        float inv = 1.f / (e0 + e1 + e2 + e3);
        gsh[0] = e0 * inv; gsh[1] = e1 * inv; gsh[2] = e2 * inv; gsh[3] = e3 * inv;
    }
    __syncthreads();
    const float g0 = gsh[0], g1 = gsh[1], g2 = gsh[2], g3 = gsh[3];
    for (int idx = t; idx < COUT * CIN; idx += 256) {
        float w = g0 * expert_w[idx]
                + g1 * expert_w[COUT * CIN + idx]
                + g2 * expert_w[2 * COUT * CIN + idx]
                + g3 * expert_w[3 * COUT * CIN + idx];
        wmix[b * COUT * CIN + idx] = f2bf(w);
    }
}

__global__ __launch_bounds__(256, 4) void conv_fb_kernel(const float* __restrict__ x,
                                                         const short* __restrict__ wmix,
                                                         float* __restrict__ out) {
    __shared__ char wlds[COUT * 256];
    __shared__ char xlds[64 * 256];
    const int b  = blockIdx.y;
    const int p0 = blockIdx.x * 64;
    const int t  = threadIdx.x;

    {
        const uint4* __restrict__ wsrc = (const uint4*)(wmix + (size_t)b * COUT * CIN);
        #pragma unroll
        for (int pass = 0; pass < 8; ++pass) {
            int o  = (t >> 4) + pass * 16;
            int i4 = t & 15;
            uint4 v = wsrc[o * 16 + i4];
            *(uint4*)(wlds + o * 256 + ((i4 ^ (o & 15)) << 4)) = v;
        }
    }
    {
        const int pg = t & 15;
        const int cg = t >> 4;
        #pragma unroll
        for (int p = 0; p < 2; ++p) {
            const int cin0 = p * 64 + cg * 4;
            const float* xrow = x + (size_t)b * CIN * HW_ + (size_t)cin0 * HW_ + p0 + pg * 4;
            float va[4][4];
            #pragma unroll
            for (int i = 0; i < 4; ++i) {
                float4 v = *(const float4*)(xrow + (size_t)i * HW_);
                va[i][0] = v.x; va[i][1] = v.y; va[i][2] = v.z; va[i][3] = v.w;
            }
            #pragma unroll
            for (int j = 0; j < 4; ++j) {
                const int pix = pg * 4 + j;
                uint32_t lo = (uint32_t)(ushort)f2bf(va[0][j]) | ((uint32_t)(ushort)f2bf(va[1][j]) << 16);
                uint32_t hi = (uint32_t)(ushort)f2bf(va[2][j]) | ((uint32_t)(ushort)f2bf(va[3][j]) << 16);
                int byte = (pix * 256 + cin0 * 2) ^ ((pix & 7) << 4);
                uint2 w2; w2.x = lo; w2.y = hi;
                *(uint2*)(xlds + byte) = w2;
            }
        }
    }

    const int wave = t >> 6;
    const int lane = t & 63;
    const int n = lane & 15;
    const int h = lane >> 4;

    __syncthreads();

    bf16x8 xfrag[4];
    {
        const int pixl = wave * 16 + n;
        #pragma unroll
        for (int kk = 0; kk < 4; ++kk) {
            int byte = (pixl * 256 + kk * 64 + h * 16) ^ ((pixl & 7) << 4);
            xfrag[kk] = *(const bf16x8*)(xlds + byte);
        }
    }

    f32x4 acc[8];
    #pragma unroll
    for (int ot = 0; ot < 8; ++ot) acc[ot] = (f32x4){0.f, 0.f, 0.f, 0.f};

    #pragma unroll
    for (int ot = 0; ot < 8; ++ot) {
        const int o = ot * 16 + n;
        #pragma unroll
        for (int kk = 0; kk < 4; ++kk) {
            bf16x8 wfrag = *(const bf16x8*)(wlds + o * 256 + (((kk * 4 + h) ^ n) << 4));
            acc[ot] = __builtin_amdgcn_mfma_f32_16x16x32_bf16(xfrag[kk], wfrag, acc[ot], 0, 0, 0);
        }
    }

    float* __restrict__ ob = out + (size_t)b * COUT * HW_ + p0 + wave * 16 + h * 4;
    #pragma unroll
    for (int ot = 0; ot < 8; ++ot)
        __builtin_nontemporal_store(acc[ot], (f32x4*)(ob + (size_t)(ot * 16 + n) * HW_));
}

// ---------------------------------------------------------------------------
extern "C" void kernel_launch(void* const* d_in, const int* in_sizes, int n_in,
                              void* d_out, int out_size, void* d_ws, size_t ws_size,
                              hipStream_t stream) {
    const float* x        = (const float*)d_in[0];
    const float* expert_w = (const float*)d_in[1];
    const float* gate_w   = (const float*)d_in[2];
    const float* gate_b   = (const float*)d_in[3];
    float* out = (float*)d_out;

    const size_t PARTIAL_B = (size_t)B_ * NCHUNK * CIN * 4;     // 3,211,264
    const size_t WMIX_B    = (size_t)B_ * COUT * CIN * 2;       // 1,048,576
    const size_t XBF_B     = (size_t)B_ * HW_ * CIN * 2;        // 102,760,448
    const size_t NEED      = PARTIAL_B + WMIX_B + XBF_B;

    if (ws_size >= NEED) {
        float* partial = (float*)d_ws;
        short* wmix2   = (short*)((char*)d_ws + PARTIAL_B);
        short* xbf2    = (short*)((char*)d_ws + PARTIAL_B + WMIX_B);

        prep_kernel<<<dim3(NCHUNK, B_), 256, 0, stream>>>(x, xbf2, partial);
        gate2_kernel<<<dim3(B_), 256, 0, stream>>>(partial, gate_w, gate_b, expert_w, wmix2);
        conv3_kernel<<<dim3(49, B_), 256, 0, stream>>>(xbf2, wmix2, out);
    } else {
        float* pooled = (float*)d_ws;                           // 16 KB
        short* wmix   = (short*)((char*)d_ws + 16384);          // 1 MB
        pool_kernel<<<dim3(B_ * CIN), 256, 0, stream>>>(x, pooled);
        gate_kernel<<<dim3(B_), 256, 0, stream>>>(pooled, gate_w, gate_b, expert_w, wmix);
        conv_fb_kernel<<<dim3(HW_ / 64, B_), 256, 0, stream>>>(x, wmix, out);
    }
}